// Round 3
// baseline (1489.622 us; speedup 1.0000x reference)
//
#include <hip/hip_runtime.h>

#define T_TOKENS 16384
#define DM 1024      // d_model
#define DI 4096      // d_inner
#define NE 8
#define PAIRS 64     // sparse pair slots: p = lo*8+hi, lo<hi
#define NPAIRC 28    // compact active pairs (lo<hi)
#define CAP 16384    // max tokens per pair

typedef float f32x4 __attribute__((ext_vector_type(4)));
typedef __bf16 bf16x8 __attribute__((ext_vector_type(8)));

__device__ inline unsigned short f2b(float f) {
  union { float f; unsigned u; } v; v.f = f;
  unsigned r = v.u + 0x7FFFu + ((v.u >> 16) & 1u);   // round-to-nearest-even bf16
  return (unsigned short)(r >> 16);
}

// ---------------- gating: fp64 logits -> softmax scores, top-2 -> pair lists; also emit bf16 X
__global__ __launch_bounds__(256) void k_gating(
    const float* __restrict__ x, const float* __restrict__ gw, const float* __restrict__ gb,
    unsigned short* __restrict__ x16, float* __restrict__ scores,
    int* __restrict__ cnt, int* __restrict__ ptok)
{
  int wid  = (blockIdx.x * 256 + threadIdx.x) >> 6;   // one wave per token
  int lane = threadIdx.x & 63;
  if (wid >= T_TOKENS) return;
  const float* xr = x + (size_t)wid * DM;

  double acc[NE];
  #pragma unroll
  for (int e = 0; e < NE; e++) acc[e] = 0.0;

  #pragma unroll
  for (int u = 0; u < 4; u++) {
    int off = u * 256 + lane * 4;
    float4 xv = *(const float4*)(xr + off);
    ushort4 pk; pk.x = f2b(xv.x); pk.y = f2b(xv.y); pk.z = f2b(xv.z); pk.w = f2b(xv.w);
    *(ushort4*)(x16 + (size_t)wid * DM + off) = pk;
    #pragma unroll
    for (int e = 0; e < NE; e++) {
      float4 wv = *(const float4*)(gw + e * DM + off);
      acc[e] += (double)xv.x * wv.x + (double)xv.y * wv.y
              + (double)xv.z * wv.z + (double)xv.w * wv.w;
    }
  }
  #pragma unroll
  for (int e = 0; e < NE; e++) {
    double v = acc[e];
    #pragma unroll
    for (int s = 32; s > 0; s >>= 1) v += __shfl_xor(v, s, 64);
    acc[e] = v + (double)gb[e];
  }
  if (lane == 0) {
    double m = acc[0];
    for (int e = 1; e < NE; e++) if (acc[e] > m) m = acc[e];
    double ex[NE], sum = 0.0;
    for (int e = 0; e < NE; e++) { ex[e] = exp(acc[e] - m); sum += ex[e]; }
    double inv = 1.0 / sum;
    for (int e = 0; e < NE; e++) scores[(size_t)wid * NE + e] = (float)(ex[e] * inv);
    int e1 = 0; double b1 = acc[0];
    for (int e = 1; e < NE; e++) if (acc[e] > b1) { b1 = acc[e]; e1 = e; }
    int e2 = -1; double b2 = -1e300;
    for (int e = 0; e < NE; e++) if (e != e1 && acc[e] > b2) { b2 = acc[e]; e2 = e; }
    int lo = e1 < e2 ? e1 : e2, hi = e1 < e2 ? e2 : e1;
    int p = lo * 8 + hi;
    int pos = atomicAdd(&cnt[p], 1);
    ptok[p * CAP + pos] = wid;
  }
}

// ---------------- expert_w fp32 -> bf16 per-expert (fallback path only)
__global__ __launch_bounds__(256) void k_wconv(const float* __restrict__ w, unsigned short* __restrict__ w16) {
  size_t i = ((size_t)blockIdx.x * 256 + threadIdx.x) * 8;
  float4 a = *(const float4*)(w + i);
  float4 b = *(const float4*)(w + i + 4);
  ushort4 pa, pb;
  pa.x = f2b(a.x); pa.y = f2b(a.y); pa.z = f2b(a.z); pa.w = f2b(a.w);
  pb.x = f2b(b.x); pb.y = f2b(b.y); pb.z = f2b(b.z); pb.w = f2b(b.w);
  *(ushort4*)(w16 + i) = pa;
  *(ushort4*)(w16 + i + 4) = pb;
}

// ---------------- pair-averaged weights: wp[idx(lo,hi)] = bf16(0.5*(W_lo + W_hi))
// fp32 sum, single bf16 rounding. Each thread: one float4 position across all 8 experts.
__global__ __launch_bounds__(256) void k_wpair(const float* __restrict__ w, unsigned short* __restrict__ wp) {
  size_t i = ((size_t)blockIdx.x * 256 + threadIdx.x) * 4;   // float index within one DI*DM matrix
  float4 v[NE];
  #pragma unroll
  for (int e = 0; e < NE; e++) v[e] = *(const float4*)(w + (size_t)e * (DI * (size_t)DM) + i);
  int idx = 0;
  #pragma unroll
  for (int lo = 0; lo < NE; lo++) {
    #pragma unroll
    for (int hi = lo + 1; hi < NE; hi++) {
      ushort4 pk;
      pk.x = f2b(0.5f * (v[lo].x + v[hi].x));
      pk.y = f2b(0.5f * (v[lo].y + v[hi].y));
      pk.z = f2b(0.5f * (v[lo].z + v[hi].z));
      pk.w = f2b(0.5f * (v[lo].w + v[hi].w));
      *(ushort4*)(wp + (size_t)idx * (DI * (size_t)DM) + i) = pk;
      idx++;
    }
  }
}

// ---------------- tile scheduler: wave-parallel scan over 64 pairs
__global__ void k_sched(const int* __restrict__ cnt, int* __restrict__ tiles, int* __restrict__ ntiles) {
  int p = threadIdx.x;            // 0..63, one wave
  int c = cnt[p];
  int nt = (c + 127) >> 7;
  int inc = nt;
  #pragma unroll
  for (int s = 1; s < 64; s <<= 1) {
    int v = __shfl_up(inc, s, 64);
    if (p >= s) inc += v;
  }
  int excl = inc - nt;
  for (int i = 0; i < nt; i++) { tiles[2 * (excl + i)] = p; tiles[2 * (excl + i) + 1] = i * 128; }
  if (p == 63) *ntiles = inc;
}

// ---------------- grouped GEMM (pair-weight path): Y = X_gather @ W_pair^T, one MFMA/acc.
// Proven R1 structure: BK=64, 2-barrier K-loop, global_load_lds staging, XOR swizzle
// (chunk ^= row&7 at the GLOBAL source), wave-uniform tail-skip. LDS 32KB -> 5 blocks/CU.
__global__ __launch_bounds__(256, 5) void k_gemm_pair(
    const unsigned short* __restrict__ x16, const unsigned short* __restrict__ wp,
    const float* __restrict__ eb, const int* __restrict__ cnt,
    const int* __restrict__ ptok, const int* __restrict__ tiles, const int* __restrict__ ntiles,
    float* __restrict__ out)
{
  __shared__ unsigned short As[128 * 64];
  __shared__ unsigned short Bs[128 * 64];

  int tileIdx = blockIdx.y;
  if (tileIdx >= *ntiles) return;
  int p    = tiles[2 * tileIdx];
  int row0 = tiles[2 * tileIdx + 1];
  int e1 = p >> 3, e2 = p & 7;
  int pidx = e1 * 7 - ((e1 * (e1 - 1)) >> 1) + (e2 - e1 - 1);   // compact pair index 0..27
  int c  = cnt[p];
  int nTile = blockIdx.x;           // 0..31 over d_inner
  int tid  = threadIdx.x;
  int lane = tid & 63;
  int wid  = tid >> 6;
  int waveM = wid >> 1, waveN = wid & 1;

  int rlim = c - row0 - waveM * 64;     // fragment mi live iff mi*16 < rlim

  int tok[4];
  #pragma unroll
  for (int i = 0; i < 4; i++) {
    int rg = row0 + (tid >> 3) + i * 32;
    if (rg > c - 1) rg = c - 1;
    tok[i] = ptok[p * CAP + rg];
  }

  f32x4 acc[4][4];
  #pragma unroll
  for (int i = 0; i < 4; i++)
    #pragma unroll
    for (int j = 0; j < 4; j++) acc[i][j] = {0.f, 0.f, 0.f, 0.f};

  const unsigned short* bb = wp + ((size_t)pidx * DI + (size_t)nTile * 128) * DM;

  for (int k0 = 0; k0 < DM; k0 += 64) {
    #pragma unroll
    for (int i = 0; i < 4; i++) {
      int r  = (tid >> 3) + i * 32;
      int cS = tid & 7;
      int kg = ((cS ^ (r & 7)) * 8);
      __builtin_amdgcn_global_load_lds(
          (const __attribute__((address_space(1))) void*)(x16 + (size_t)tok[i] * DM + k0 + kg),
          (__attribute__((address_space(3))) void*)(&As[r * 64 + cS * 8]), 16, 0, 0);
      __builtin_amdgcn_global_load_lds(
          (const __attribute__((address_space(1))) void*)(bb + (size_t)r * DM + k0 + kg),
          (__attribute__((address_space(3))) void*)(&Bs[r * 64 + cS * 8]), 16, 0, 0);
    }
    __syncthreads();
    #pragma unroll
    for (int kk = 0; kk < 2; kk++) {
      int q  = lane >> 4;
      int m  = lane & 15;
      int jg = kk * 4 + q;
      bf16x8 af[4], bf[4];
      #pragma unroll
      for (int mi = 0; mi < 4; mi++) {
        if (mi * 16 < rlim) {
          int R = waveM * 64 + mi * 16 + m;
          af[mi] = *(const bf16x8*)&As[R * 64 + ((jg ^ (R & 7)) * 8)];
        }
      }
      #pragma unroll
      for (int ni = 0; ni < 4; ni++) {
        int R = waveN * 64 + ni * 16 + m;
        bf[ni] = *(const bf16x8*)&Bs[R * 64 + ((jg ^ (R & 7)) * 8)];
      }
      #pragma unroll
      for (int mi = 0; mi < 4; mi++) {
        if (mi * 16 < rlim) {
          #pragma unroll
          for (int ni = 0; ni < 4; ni++)
            acc[mi][ni] = __builtin_amdgcn_mfma_f32_16x16x32_bf16(af[mi], bf[ni], acc[mi][ni], 0, 0, 0);
        }
      }
    }
    __syncthreads();
  }

  // epilogue: W_pair already carries the 0.5; biases still need it.
  int colbase = nTile * 128 + waveN * 64;
  float bsum[4];
  #pragma unroll
  for (int ni = 0; ni < 4; ni++) {
    int col = colbase + ni * 16 + (lane & 15);
    bsum[ni] = 0.5f * (eb[e1 * DI + col] + eb[e2 * DI + col]);
  }
  #pragma unroll
  for (int mi = 0; mi < 4; mi++) {
    #pragma unroll
    for (int r2 = 0; r2 < 4; r2++) {
      int row = waveM * 64 + mi * 16 + (lane >> 4) * 4 + r2;
      int rg = row0 + row;
      if (rg < c) {
        int t = ptok[p * CAP + rg];
        float* orow = out + (size_t)t * DI + colbase;
        #pragma unroll
        for (int ni = 0; ni < 4; ni++)
          orow[ni * 16 + (lane & 15)] = acc[mi][ni][r2] + bsum[ni];
      }
    }
  }
}

// ---------------- grouped GEMM (fallback, R1-verified dual-expert version)
__global__ __launch_bounds__(256) void k_gemm_dual(
    const unsigned short* __restrict__ x16, const unsigned short* __restrict__ w16,
    const float* __restrict__ eb, const int* __restrict__ cnt,
    const int* __restrict__ ptok, const int* __restrict__ tiles, const int* __restrict__ ntiles,
    float* __restrict__ out)
{
  __shared__ unsigned short As[128 * 64];
  __shared__ unsigned short Bs[2][128 * 64];

  int tileIdx = blockIdx.y;
  if (tileIdx >= *ntiles) return;
  int p    = tiles[2 * tileIdx];
  int row0 = tiles[2 * tileIdx + 1];
  int e1 = p >> 3, e2 = p & 7;
  int c  = cnt[p];
  int nTile = blockIdx.x;
  int tid  = threadIdx.x;
  int lane = tid & 63;
  int wid  = tid >> 6;
  int waveM = wid >> 1, waveN = wid & 1;
  int rlim = c - row0 - waveM * 64;

  int tok[4];
  #pragma unroll
  for (int i = 0; i < 4; i++) {
    int rg = row0 + (tid >> 3) + i * 32;
    if (rg > c - 1) rg = c - 1;
    tok[i] = ptok[p * CAP + rg];
  }

  f32x4 acc[4][4];
  #pragma unroll
  for (int i = 0; i < 4; i++)
    #pragma unroll
    for (int j = 0; j < 4; j++) acc[i][j] = {0.f, 0.f, 0.f, 0.f};

  const unsigned short* bb1 = w16 + ((size_t)e1 * DI + (size_t)nTile * 128) * DM;
  const unsigned short* bb2 = w16 + ((size_t)e2 * DI + (size_t)nTile * 128) * DM;

  for (int k0 = 0; k0 < DM; k0 += 64) {
    #pragma unroll
    for (int i = 0; i < 4; i++) {
      int r  = (tid >> 3) + i * 32;
      int cS = tid & 7;
      int kg = ((cS ^ (r & 7)) * 8);
      __builtin_amdgcn_global_load_lds(
          (const __attribute__((address_space(1))) void*)(x16 + (size_t)tok[i] * DM + k0 + kg),
          (__attribute__((address_space(3))) void*)(&As[r * 64 + cS * 8]), 16, 0, 0);
      __builtin_amdgcn_global_load_lds(
          (const __attribute__((address_space(1))) void*)(bb1 + (size_t)r * DM + k0 + kg),
          (__attribute__((address_space(3))) void*)(&Bs[0][r * 64 + cS * 8]), 16, 0, 0);
      __builtin_amdgcn_global_load_lds(
          (const __attribute__((address_space(1))) void*)(bb2 + (size_t)r * DM + k0 + kg),
          (__attribute__((address_space(3))) void*)(&Bs[1][r * 64 + cS * 8]), 16, 0, 0);
    }
    __syncthreads();
    #pragma unroll
    for (int kk = 0; kk < 2; kk++) {
      int q  = lane >> 4;
      int m  = lane & 15;
      int jg = kk * 4 + q;
      bf16x8 af[4], bf0[4], bf1[4];
      #pragma unroll
      for (int mi = 0; mi < 4; mi++) {
        if (mi * 16 < rlim) {
          int R = waveM * 64 + mi * 16 + m;
          af[mi] = *(const bf16x8*)&As[R * 64 + ((jg ^ (R & 7)) * 8)];
        }
      }
      #pragma unroll
      for (int ni = 0; ni < 4; ni++) {
        int R = waveN * 64 + ni * 16 + m;
        int o = R * 64 + ((jg ^ (R & 7)) * 8);
        bf0[ni] = *(const bf16x8*)&Bs[0][o];
        bf1[ni] = *(const bf16x8*)&Bs[1][o];
      }
      #pragma unroll
      for (int mi = 0; mi < 4; mi++) {
        if (mi * 16 < rlim) {
          #pragma unroll
          for (int ni = 0; ni < 4; ni++) {
            acc[mi][ni] = __builtin_amdgcn_mfma_f32_16x16x32_bf16(af[mi], bf0[ni], acc[mi][ni], 0, 0, 0);
            acc[mi][ni] = __builtin_amdgcn_mfma_f32_16x16x32_bf16(af[mi], bf1[ni], acc[mi][ni], 0, 0, 0);
          }
        }
      }
    }
    __syncthreads();
  }

  int colbase = nTile * 128 + waveN * 64;
  float bsum[4];
  #pragma unroll
  for (int ni = 0; ni < 4; ni++) {
    int col = colbase + ni * 16 + (lane & 15);
    bsum[ni] = 0.5f * (eb[e1 * DI + col] + eb[e2 * DI + col]);
  }
  #pragma unroll
  for (int mi = 0; mi < 4; mi++) {
    #pragma unroll
    for (int r2 = 0; r2 < 4; r2++) {
      int row = waveM * 64 + mi * 16 + (lane >> 4) * 4 + r2;
      int rg = row0 + row;
      if (rg < c) {
        int t = ptok[p * CAP + rg];
        float* orow = out + (size_t)t * DI + colbase;
        #pragma unroll
        for (int ni = 0; ni < 4; ni++)
          orow[ni * 16 + (lane & 15)] = 0.5f * acc[mi][ni][r2] + bsum[ni];
      }
    }
  }
}

// ---------------- per-expert unbiased variance of softmax scores
__global__ __launch_bounds__(256) void k_var(const float* __restrict__ scores, float* __restrict__ vout) {
  int e = blockIdx.x, tid = threadIdx.x;
  double s = 0.0, s2 = 0.0;
  for (int t = tid; t < T_TOKENS; t += 256) {
    double v = (double)scores[(size_t)t * NE + e];
    s += v; s2 += v * v;
  }
  __shared__ double ls[256], ls2[256];
  ls[tid] = s; ls2[tid] = s2; __syncthreads();
  for (int st = 128; st > 0; st >>= 1) {
    if (tid < st) { ls[tid] += ls[tid + st]; ls2[tid] += ls2[tid + st]; }
    __syncthreads();
  }
  if (tid == 0) {
    double mean = ls[0] / (double)T_TOKENS;
    vout[e] = (float)((ls2[0] - ls[0] * mean) / (double)(T_TOKENS - 1));
  }
}

extern "C" void kernel_launch(void* const* d_in, const int* in_sizes, int n_in,
                              void* d_out, int out_size, void* d_ws, size_t ws_size,
                              hipStream_t stream)
{
  const float* x  = (const float*)d_in[0];
  const float* gw = (const float*)d_in[1];
  const float* gb = (const float*)d_in[2];
  const float* ew = (const float*)d_in[3];
  const float* eb = (const float*)d_in[4];
  float* out = (float*)d_out;
  char* ws = (char*)d_ws;

  // ---- pair path workspace (273.2 MB) ----
  const size_t OFF_WPAIR  = 33554432ull;                         // after x16 (33.5 MB)
  const size_t OFF_SCORES = OFF_WPAIR + (size_t)NPAIRC * DI * DM * 2; // +234,881,024
  const size_t OFF_PTOK   = OFF_SCORES + 524288ull;
  const size_t OFF_CNT    = OFF_PTOK + 4194304ull;
  const size_t OFF_NT     = OFF_CNT + 256ull;
  const size_t OFF_TILES  = OFF_NT + 16ull;
  const size_t NEED_PAIR  = OFF_TILES + 1536ull;

  if (ws_size >= NEED_PAIR) {
    unsigned short* x16 = (unsigned short*)ws;
    unsigned short* wp  = (unsigned short*)(ws + OFF_WPAIR);
    float* scores       = (float*)(ws + OFF_SCORES);
    int*   ptok         = (int*)(ws + OFF_PTOK);
    int*   cnt          = (int*)(ws + OFF_CNT);
    int*   ntiles       = (int*)(ws + OFF_NT);
    int*   tiles        = (int*)(ws + OFF_TILES);

    hipMemsetAsync(cnt, 0, PAIRS * sizeof(int), stream);
    k_gating<<<dim3(4096), dim3(256), 0, stream>>>(x, gw, gb, x16, scores, cnt, ptok);
    k_wpair <<<dim3(4096), dim3(256), 0, stream>>>(ew, wp);      // 1M float4 positions
    k_sched <<<dim3(1), dim3(64), 0, stream>>>(cnt, tiles, ntiles);
    k_gemm_pair<<<dim3(32, 192), dim3(256), 0, stream>>>(x16, wp, eb, cnt, ptok, tiles, ntiles, out);
    k_var   <<<dim3(8), dim3(256), 0, stream>>>(scores, out + 67108864);
  } else {
    // ---- fallback: R1-verified layout (~105.4 MB) ----
    unsigned short* x16 = (unsigned short*)ws;
    unsigned short* w16 = (unsigned short*)(ws + 33554432);
    float* scores       = (float*)(ws + 100663296);
    int*   ptok         = (int*)(ws + 101187584);
    int*   cnt          = (int*)(ws + 105381888);
    int*   ntiles       = (int*)(ws + 105382144);
    int*   tiles        = (int*)(ws + 105382160);

    hipMemsetAsync(cnt, 0, PAIRS * sizeof(int), stream);
    k_gating<<<dim3(4096), dim3(256), 0, stream>>>(x, gw, gb, x16, scores, cnt, ptok);
    k_wconv <<<dim3(16384), dim3(256), 0, stream>>>(ew, w16);
    k_sched <<<dim3(1), dim3(64), 0, stream>>>(cnt, tiles, ntiles);
    k_gemm_dual<<<dim3(32, 192), dim3(256), 0, stream>>>(x16, w16, eb, cnt, ptok, tiles, ntiles, out);
    k_var   <<<dim3(8), dim3(256), 0, stream>>>(scores, out + 67108864);
  }
}

// Round 4
// 759.831 us; speedup vs baseline: 1.9605x; 1.9605x over previous
//
#include <hip/hip_runtime.h>

#define T_TOKENS 16384
#define DM 1024      // d_model
#define DI 4096      // d_inner
#define NE 8
#define PAIRS 64     // sparse pair slots: p = lo*8+hi, lo<hi
#define NPAIRC 28    // compact active pairs (lo<hi)
#define CAP 16384    // max tokens per pair

typedef float f32x4 __attribute__((ext_vector_type(4)));
typedef __bf16 bf16x8 __attribute__((ext_vector_type(8)));

__device__ inline unsigned short f2b(float f) {
  union { float f; unsigned u; } v; v.f = f;
  unsigned r = v.u + 0x7FFFu + ((v.u >> 16) & 1u);   // round-to-nearest-even bf16
  return (unsigned short)(r >> 16);
}

// ---------------- gating: fp64 logits -> softmax scores, top-2 -> pair lists; also emit bf16 X
__global__ __launch_bounds__(256) void k_gating(
    const float* __restrict__ x, const float* __restrict__ gw, const float* __restrict__ gb,
    unsigned short* __restrict__ x16, float* __restrict__ scores,
    int* __restrict__ cnt, int* __restrict__ ptok)
{
  int wid  = (blockIdx.x * 256 + threadIdx.x) >> 6;   // one wave per token
  int lane = threadIdx.x & 63;
  if (wid >= T_TOKENS) return;
  const float* xr = x + (size_t)wid * DM;

  double acc[NE];
  #pragma unroll
  for (int e = 0; e < NE; e++) acc[e] = 0.0;

  #pragma unroll
  for (int u = 0; u < 4; u++) {
    int off = u * 256 + lane * 4;
    float4 xv = *(const float4*)(xr + off);
    ushort4 pk; pk.x = f2b(xv.x); pk.y = f2b(xv.y); pk.z = f2b(xv.z); pk.w = f2b(xv.w);
    *(ushort4*)(x16 + (size_t)wid * DM + off) = pk;
    #pragma unroll
    for (int e = 0; e < NE; e++) {
      float4 wv = *(const float4*)(gw + e * DM + off);
      acc[e] += (double)xv.x * wv.x + (double)xv.y * wv.y
              + (double)xv.z * wv.z + (double)xv.w * wv.w;
    }
  }
  #pragma unroll
  for (int e = 0; e < NE; e++) {
    double v = acc[e];
    #pragma unroll
    for (int s = 32; s > 0; s >>= 1) v += __shfl_xor(v, s, 64);
    acc[e] = v + (double)gb[e];
  }
  if (lane == 0) {
    double m = acc[0];
    for (int e = 1; e < NE; e++) if (acc[e] > m) m = acc[e];
    double ex[NE], sum = 0.0;
    for (int e = 0; e < NE; e++) { ex[e] = exp(acc[e] - m); sum += ex[e]; }
    double inv = 1.0 / sum;
    for (int e = 0; e < NE; e++) scores[(size_t)wid * NE + e] = (float)(ex[e] * inv);
    int e1 = 0; double b1 = acc[0];
    for (int e = 1; e < NE; e++) if (acc[e] > b1) { b1 = acc[e]; e1 = e; }
    int e2 = -1; double b2 = -1e300;
    for (int e = 0; e < NE; e++) if (e != e1 && acc[e] > b2) { b2 = acc[e]; e2 = e; }
    int lo = e1 < e2 ? e1 : e2, hi = e1 < e2 ? e2 : e1;
    int p = lo * 8 + hi;
    int pos = atomicAdd(&cnt[p], 1);
    ptok[p * CAP + pos] = wid;
  }
}

// ---------------- expert_w fp32 -> bf16 per-expert (fallback path only)
__global__ __launch_bounds__(256) void k_wconv(const float* __restrict__ w, unsigned short* __restrict__ w16) {
  size_t i = ((size_t)blockIdx.x * 256 + threadIdx.x) * 8;
  float4 a = *(const float4*)(w + i);
  float4 b = *(const float4*)(w + i + 4);
  ushort4 pa, pb;
  pa.x = f2b(a.x); pa.y = f2b(a.y); pa.z = f2b(a.z); pa.w = f2b(a.w);
  pb.x = f2b(b.x); pb.y = f2b(b.y); pb.z = f2b(b.z); pb.w = f2b(b.w);
  *(ushort4*)(w16 + i) = pa;
  *(ushort4*)(w16 + i + 4) = pb;
}

// ---------------- pair-averaged weights: wp[idx(lo,hi)] = bf16(0.5*(W_lo + W_hi))
// fp32 sum, single bf16 rounding. Each thread: one float4 position across all 8 experts.
__global__ __launch_bounds__(256) void k_wpair(const float* __restrict__ w, unsigned short* __restrict__ wp) {
  size_t i = ((size_t)blockIdx.x * 256 + threadIdx.x) * 4;   // float index within one DI*DM matrix
  float4 v[NE];
  #pragma unroll
  for (int e = 0; e < NE; e++) v[e] = *(const float4*)(w + (size_t)e * (DI * (size_t)DM) + i);
  int idx = 0;
  #pragma unroll
  for (int lo = 0; lo < NE; lo++) {
    #pragma unroll
    for (int hi = lo + 1; hi < NE; hi++) {
      ushort4 pk;
      pk.x = f2b(0.5f * (v[lo].x + v[hi].x));
      pk.y = f2b(0.5f * (v[lo].y + v[hi].y));
      pk.z = f2b(0.5f * (v[lo].z + v[hi].z));
      pk.w = f2b(0.5f * (v[lo].w + v[hi].w));
      *(ushort4*)(wp + (size_t)idx * (DI * (size_t)DM) + i) = pk;
      idx++;
    }
  }
}

// ---------------- tile scheduler: wave-parallel scan over 64 pairs
__global__ void k_sched(const int* __restrict__ cnt, int* __restrict__ tiles, int* __restrict__ ntiles) {
  int p = threadIdx.x;            // 0..63, one wave
  int c = cnt[p];
  int nt = (c + 127) >> 7;
  int inc = nt;
  #pragma unroll
  for (int s = 1; s < 64; s <<= 1) {
    int v = __shfl_up(inc, s, 64);
    if (p >= s) inc += v;
  }
  int excl = inc - nt;
  for (int i = 0; i < nt; i++) { tiles[2 * (excl + i)] = p; tiles[2 * (excl + i) + 1] = i * 128; }
  if (p == 63) *ntiles = inc;
}

// ---------------- grouped GEMM (pair-weight path): Y = X_gather @ W_pair^T, one MFMA/acc.
// R1-proven structure: BK=64, 2-barrier K-loop, global_load_lds staging, XOR swizzle
// (chunk ^= row&7 at the GLOBAL source), wave-uniform tail-skip. LDS 32KB.
// NOTE: no min-occupancy launch bound — R3's (256,5) forced a 102-reg/wave budget and
// spilled the 64-AGPR accumulator to scratch (WRITE_SIZE 10x, 1000us). Registers need
// ~112/wave -> allocator-free gives ~4 blocks/CU, no spill.
__global__ __launch_bounds__(256) void k_gemm_pair(
    const unsigned short* __restrict__ x16, const unsigned short* __restrict__ wp,
    const float* __restrict__ eb, const int* __restrict__ cnt,
    const int* __restrict__ ptok, const int* __restrict__ tiles, const int* __restrict__ ntiles,
    float* __restrict__ out)
{
  __shared__ unsigned short As[128 * 64];
  __shared__ unsigned short Bs[128 * 64];

  int tileIdx = blockIdx.y;
  if (tileIdx >= *ntiles) return;
  int p    = tiles[2 * tileIdx];
  int row0 = tiles[2 * tileIdx + 1];
  int e1 = p >> 3, e2 = p & 7;
  int pidx = e1 * 7 - ((e1 * (e1 - 1)) >> 1) + (e2 - e1 - 1);   // compact pair index 0..27
  int c  = cnt[p];
  int nTile = blockIdx.x;           // 0..31 over d_inner
  int tid  = threadIdx.x;
  int lane = tid & 63;
  int wid  = tid >> 6;
  int waveM = wid >> 1, waveN = wid & 1;

  int rlim = c - row0 - waveM * 64;     // fragment mi live iff mi*16 < rlim

  int tok[4];
  #pragma unroll
  for (int i = 0; i < 4; i++) {
    int rg = row0 + (tid >> 3) + i * 32;
    if (rg > c - 1) rg = c - 1;
    tok[i] = ptok[p * CAP + rg];
  }

  f32x4 acc[4][4];
  #pragma unroll
  for (int i = 0; i < 4; i++)
    #pragma unroll
    for (int j = 0; j < 4; j++) acc[i][j] = {0.f, 0.f, 0.f, 0.f};

  const unsigned short* bb = wp + ((size_t)pidx * DI + (size_t)nTile * 128) * DM;

  for (int k0 = 0; k0 < DM; k0 += 64) {
    #pragma unroll
    for (int i = 0; i < 4; i++) {
      int r  = (tid >> 3) + i * 32;
      int cS = tid & 7;
      int kg = ((cS ^ (r & 7)) * 8);
      __builtin_amdgcn_global_load_lds(
          (const __attribute__((address_space(1))) void*)(x16 + (size_t)tok[i] * DM + k0 + kg),
          (__attribute__((address_space(3))) void*)(&As[r * 64 + cS * 8]), 16, 0, 0);
      __builtin_amdgcn_global_load_lds(
          (const __attribute__((address_space(1))) void*)(bb + (size_t)r * DM + k0 + kg),
          (__attribute__((address_space(3))) void*)(&Bs[r * 64 + cS * 8]), 16, 0, 0);
    }
    __syncthreads();
    #pragma unroll
    for (int kk = 0; kk < 2; kk++) {
      int q  = lane >> 4;
      int m  = lane & 15;
      int jg = kk * 4 + q;
      bf16x8 af[4], bf[4];
      #pragma unroll
      for (int mi = 0; mi < 4; mi++) {
        if (mi * 16 < rlim) {
          int R = waveM * 64 + mi * 16 + m;
          af[mi] = *(const bf16x8*)&As[R * 64 + ((jg ^ (R & 7)) * 8)];
        }
      }
      #pragma unroll
      for (int ni = 0; ni < 4; ni++) {
        int R = waveN * 64 + ni * 16 + m;
        bf[ni] = *(const bf16x8*)&Bs[R * 64 + ((jg ^ (R & 7)) * 8)];
      }
      #pragma unroll
      for (int mi = 0; mi < 4; mi++) {
        if (mi * 16 < rlim) {
          #pragma unroll
          for (int ni = 0; ni < 4; ni++)
            acc[mi][ni] = __builtin_amdgcn_mfma_f32_16x16x32_bf16(af[mi], bf[ni], acc[mi][ni], 0, 0, 0);
        }
      }
    }
    __syncthreads();
  }

  // epilogue: W_pair already carries the 0.5; biases still need it.
  int colbase = nTile * 128 + waveN * 64;
  float bsum[4];
  #pragma unroll
  for (int ni = 0; ni < 4; ni++) {
    int col = colbase + ni * 16 + (lane & 15);
    bsum[ni] = 0.5f * (eb[e1 * DI + col] + eb[e2 * DI + col]);
  }
  #pragma unroll
  for (int mi = 0; mi < 4; mi++) {
    #pragma unroll
    for (int r2 = 0; r2 < 4; r2++) {
      int row = waveM * 64 + mi * 16 + (lane >> 4) * 4 + r2;
      int rg = row0 + row;
      if (rg < c) {
        int t = ptok[p * CAP + rg];
        float* orow = out + (size_t)t * DI + colbase;
        #pragma unroll
        for (int ni = 0; ni < 4; ni++)
          orow[ni * 16 + (lane & 15)] = acc[mi][ni][r2] + bsum[ni];
      }
    }
  }
}

// ---------------- grouped GEMM (fallback, R1-verified dual-expert version)
__global__ __launch_bounds__(256) void k_gemm_dual(
    const unsigned short* __restrict__ x16, const unsigned short* __restrict__ w16,
    const float* __restrict__ eb, const int* __restrict__ cnt,
    const int* __restrict__ ptok, const int* __restrict__ tiles, const int* __restrict__ ntiles,
    float* __restrict__ out)
{
  __shared__ unsigned short As[128 * 64];
  __shared__ unsigned short Bs[2][128 * 64];

  int tileIdx = blockIdx.y;
  if (tileIdx >= *ntiles) return;
  int p    = tiles[2 * tileIdx];
  int row0 = tiles[2 * tileIdx + 1];
  int e1 = p >> 3, e2 = p & 7;
  int c  = cnt[p];
  int nTile = blockIdx.x;
  int tid  = threadIdx.x;
  int lane = tid & 63;
  int wid  = tid >> 6;
  int waveM = wid >> 1, waveN = wid & 1;
  int rlim = c - row0 - waveM * 64;

  int tok[4];
  #pragma unroll
  for (int i = 0; i < 4; i++) {
    int rg = row0 + (tid >> 3) + i * 32;
    if (rg > c - 1) rg = c - 1;
    tok[i] = ptok[p * CAP + rg];
  }

  f32x4 acc[4][4];
  #pragma unroll
  for (int i = 0; i < 4; i++)
    #pragma unroll
    for (int j = 0; j < 4; j++) acc[i][j] = {0.f, 0.f, 0.f, 0.f};

  const unsigned short* bb1 = w16 + ((size_t)e1 * DI + (size_t)nTile * 128) * DM;
  const unsigned short* bb2 = w16 + ((size_t)e2 * DI + (size_t)nTile * 128) * DM;

  for (int k0 = 0; k0 < DM; k0 += 64) {
    #pragma unroll
    for (int i = 0; i < 4; i++) {
      int r  = (tid >> 3) + i * 32;
      int cS = tid & 7;
      int kg = ((cS ^ (r & 7)) * 8);
      __builtin_amdgcn_global_load_lds(
          (const __attribute__((address_space(1))) void*)(x16 + (size_t)tok[i] * DM + k0 + kg),
          (__attribute__((address_space(3))) void*)(&As[r * 64 + cS * 8]), 16, 0, 0);
      __builtin_amdgcn_global_load_lds(
          (const __attribute__((address_space(1))) void*)(bb1 + (size_t)r * DM + k0 + kg),
          (__attribute__((address_space(3))) void*)(&Bs[0][r * 64 + cS * 8]), 16, 0, 0);
      __builtin_amdgcn_global_load_lds(
          (const __attribute__((address_space(1))) void*)(bb2 + (size_t)r * DM + k0 + kg),
          (__attribute__((address_space(3))) void*)(&Bs[1][r * 64 + cS * 8]), 16, 0, 0);
    }
    __syncthreads();
    #pragma unroll
    for (int kk = 0; kk < 2; kk++) {
      int q  = lane >> 4;
      int m  = lane & 15;
      int jg = kk * 4 + q;
      bf16x8 af[4], bf0[4], bf1[4];
      #pragma unroll
      for (int mi = 0; mi < 4; mi++) {
        if (mi * 16 < rlim) {
          int R = waveM * 64 + mi * 16 + m;
          af[mi] = *(const bf16x8*)&As[R * 64 + ((jg ^ (R & 7)) * 8)];
        }
      }
      #pragma unroll
      for (int ni = 0; ni < 4; ni++) {
        int R = waveN * 64 + ni * 16 + m;
        int o = R * 64 + ((jg ^ (R & 7)) * 8);
        bf0[ni] = *(const bf16x8*)&Bs[0][o];
        bf1[ni] = *(const bf16x8*)&Bs[1][o];
      }
      #pragma unroll
      for (int mi = 0; mi < 4; mi++) {
        if (mi * 16 < rlim) {
          #pragma unroll
          for (int ni = 0; ni < 4; ni++) {
            acc[mi][ni] = __builtin_amdgcn_mfma_f32_16x16x32_bf16(af[mi], bf0[ni], acc[mi][ni], 0, 0, 0);
            acc[mi][ni] = __builtin_amdgcn_mfma_f32_16x16x32_bf16(af[mi], bf1[ni], acc[mi][ni], 0, 0, 0);
          }
        }
      }
    }
    __syncthreads();
  }

  int colbase = nTile * 128 + waveN * 64;
  float bsum[4];
  #pragma unroll
  for (int ni = 0; ni < 4; ni++) {
    int col = colbase + ni * 16 + (lane & 15);
    bsum[ni] = 0.5f * (eb[e1 * DI + col] + eb[e2 * DI + col]);
  }
  #pragma unroll
  for (int mi = 0; mi < 4; mi++) {
    #pragma unroll
    for (int r2 = 0; r2 < 4; r2++) {
      int row = waveM * 64 + mi * 16 + (lane >> 4) * 4 + r2;
      int rg = row0 + row;
      if (rg < c) {
        int t = ptok[p * CAP + rg];
        float* orow = out + (size_t)t * DI + colbase;
        #pragma unroll
        for (int ni = 0; ni < 4; ni++)
          orow[ni * 16 + (lane & 15)] = 0.5f * acc[mi][ni][r2] + bsum[ni];
      }
    }
  }
}

// ---------------- per-expert unbiased variance of softmax scores
__global__ __launch_bounds__(256) void k_var(const float* __restrict__ scores, float* __restrict__ vout) {
  int e = blockIdx.x, tid = threadIdx.x;
  double s = 0.0, s2 = 0.0;
  for (int t = tid; t < T_TOKENS; t += 256) {
    double v = (double)scores[(size_t)t * NE + e];
    s += v; s2 += v * v;
  }
  __shared__ double ls[256], ls2[256];
  ls[tid] = s; ls2[tid] = s2; __syncthreads();
  for (int st = 128; st > 0; st >>= 1) {
    if (tid < st) { ls[tid] += ls[tid + st]; ls2[tid] += ls2[tid + st]; }
    __syncthreads();
  }
  if (tid == 0) {
    double mean = ls[0] / (double)T_TOKENS;
    vout[e] = (float)((ls2[0] - ls[0] * mean) / (double)(T_TOKENS - 1));
  }
}

extern "C" void kernel_launch(void* const* d_in, const int* in_sizes, int n_in,
                              void* d_out, int out_size, void* d_ws, size_t ws_size,
                              hipStream_t stream)
{
  const float* x  = (const float*)d_in[0];
  const float* gw = (const float*)d_in[1];
  const float* gb = (const float*)d_in[2];
  const float* ew = (const float*)d_in[3];
  const float* eb = (const float*)d_in[4];
  float* out = (float*)d_out;
  char* ws = (char*)d_ws;

  // ---- pair path workspace (273.2 MB) ----
  const size_t OFF_WPAIR  = 33554432ull;                         // after x16 (33.5 MB)
  const size_t OFF_SCORES = OFF_WPAIR + (size_t)NPAIRC * DI * DM * 2; // +234,881,024
  const size_t OFF_PTOK   = OFF_SCORES + 524288ull;
  const size_t OFF_CNT    = OFF_PTOK + 4194304ull;
  const size_t OFF_NT     = OFF_CNT + 256ull;
  const size_t OFF_TILES  = OFF_NT + 16ull;
  const size_t NEED_PAIR  = OFF_TILES + 1536ull;

  if (ws_size >= NEED_PAIR) {
    unsigned short* x16 = (unsigned short*)ws;
    unsigned short* wp  = (unsigned short*)(ws + OFF_WPAIR);
    float* scores       = (float*)(ws + OFF_SCORES);
    int*   ptok         = (int*)(ws + OFF_PTOK);
    int*   cnt          = (int*)(ws + OFF_CNT);
    int*   ntiles       = (int*)(ws + OFF_NT);
    int*   tiles        = (int*)(ws + OFF_TILES);

    hipMemsetAsync(cnt, 0, PAIRS * sizeof(int), stream);
    k_gating<<<dim3(4096), dim3(256), 0, stream>>>(x, gw, gb, x16, scores, cnt, ptok);
    k_wpair <<<dim3(4096), dim3(256), 0, stream>>>(ew, wp);      // 1M float4 positions
    k_sched <<<dim3(1), dim3(64), 0, stream>>>(cnt, tiles, ntiles);
    k_gemm_pair<<<dim3(32, 192), dim3(256), 0, stream>>>(x16, wp, eb, cnt, ptok, tiles, ntiles, out);
    k_var   <<<dim3(8), dim3(256), 0, stream>>>(scores, out + 67108864);
  } else {
    // ---- fallback: R1-verified layout (~105.4 MB) ----
    unsigned short* x16 = (unsigned short*)ws;
    unsigned short* w16 = (unsigned short*)(ws + 33554432);
    float* scores       = (float*)(ws + 100663296);
    int*   ptok         = (int*)(ws + 101187584);
    int*   cnt          = (int*)(ws + 105381888);
    int*   ntiles       = (int*)(ws + 105382144);
    int*   tiles        = (int*)(ws + 105382160);

    hipMemsetAsync(cnt, 0, PAIRS * sizeof(int), stream);
    k_gating<<<dim3(4096), dim3(256), 0, stream>>>(x, gw, gb, x16, scores, cnt, ptok);
    k_wconv <<<dim3(16384), dim3(256), 0, stream>>>(ew, w16);
    k_sched <<<dim3(1), dim3(64), 0, stream>>>(cnt, tiles, ntiles);
    k_gemm_dual<<<dim3(32, 192), dim3(256), 0, stream>>>(x16, w16, eb, cnt, ptok, tiles, ntiles, out);
    k_var   <<<dim3(8), dim3(256), 0, stream>>>(scores, out + 67108864);
  }
}

// Round 5
// 743.280 us; speedup vs baseline: 2.0041x; 1.0223x over previous
//
#include <hip/hip_runtime.h>

#define T_TOKENS 16384
#define DM 1024      // d_model
#define DI 4096      // d_inner
#define NE 8
#define PAIRS 64     // sparse pair slots: p = lo*8+hi, lo<hi
#define NPAIRC 28    // compact active pairs (lo<hi)
#define CAP 16384    // max tokens per pair
#define TILEY 192    // max tiles: sum ceil(c_p/128) <= 128+64 = 192

typedef float f32x4 __attribute__((ext_vector_type(4)));
typedef __bf16 bf16x8 __attribute__((ext_vector_type(8)));

__device__ inline unsigned short f2b(float f) {
  union { float f; unsigned u; } v; v.f = f;
  unsigned r = v.u + 0x7FFFu + ((v.u >> 16) & 1u);   // round-to-nearest-even bf16
  return (unsigned short)(r >> 16);
}

// ---------------- fused prep: blocks 0..4095 = gating (fp64 logits -> softmax, top-2 -> pair
// lists, emit bf16 X); blocks 4096..8191 = pair-averaged weights wp = bf16(0.5*(W_lo+W_hi)).
// Identical arithmetic to the R4 k_gating / k_wpair pair; fusion only removes serialization.
__global__ __launch_bounds__(256) void k_prep(
    const float* __restrict__ x, const float* __restrict__ gw, const float* __restrict__ gb,
    const float* __restrict__ ew,
    unsigned short* __restrict__ x16, unsigned short* __restrict__ wp,
    float* __restrict__ scores, int* __restrict__ cnt, int* __restrict__ ptok)
{
  if (blockIdx.x < 4096) {
    // ---- gating ----
    int wid  = (blockIdx.x * 256 + threadIdx.x) >> 6;   // one wave per token
    int lane = threadIdx.x & 63;
    if (wid >= T_TOKENS) return;
    const float* xr = x + (size_t)wid * DM;

    double acc[NE];
    #pragma unroll
    for (int e = 0; e < NE; e++) acc[e] = 0.0;

    #pragma unroll
    for (int u = 0; u < 4; u++) {
      int off = u * 256 + lane * 4;
      float4 xv = *(const float4*)(xr + off);
      ushort4 pk; pk.x = f2b(xv.x); pk.y = f2b(xv.y); pk.z = f2b(xv.z); pk.w = f2b(xv.w);
      *(ushort4*)(x16 + (size_t)wid * DM + off) = pk;
      #pragma unroll
      for (int e = 0; e < NE; e++) {
        float4 wv = *(const float4*)(gw + e * DM + off);
        acc[e] += (double)xv.x * wv.x + (double)xv.y * wv.y
                + (double)xv.z * wv.z + (double)xv.w * wv.w;
      }
    }
    #pragma unroll
    for (int e = 0; e < NE; e++) {
      double v = acc[e];
      #pragma unroll
      for (int s = 32; s > 0; s >>= 1) v += __shfl_xor(v, s, 64);
      acc[e] = v + (double)gb[e];
    }
    if (lane == 0) {
      double m = acc[0];
      for (int e = 1; e < NE; e++) if (acc[e] > m) m = acc[e];
      double ex[NE], sum = 0.0;
      for (int e = 0; e < NE; e++) { ex[e] = exp(acc[e] - m); sum += ex[e]; }
      double inv = 1.0 / sum;
      for (int e = 0; e < NE; e++) scores[(size_t)wid * NE + e] = (float)(ex[e] * inv);
      int e1 = 0; double b1 = acc[0];
      for (int e = 1; e < NE; e++) if (acc[e] > b1) { b1 = acc[e]; e1 = e; }
      int e2 = -1; double b2 = -1e300;
      for (int e = 0; e < NE; e++) if (e != e1 && acc[e] > b2) { b2 = acc[e]; e2 = e; }
      int lo = e1 < e2 ? e1 : e2, hi = e1 < e2 ? e2 : e1;
      int p = lo * 8 + hi;
      int pos = atomicAdd(&cnt[p], 1);
      ptok[p * CAP + pos] = wid;
    }
  } else {
    // ---- wpair ----
    size_t i = (((size_t)blockIdx.x - 4096) * 256 + threadIdx.x) * 4;  // float4 index in one DI*DM matrix
    float4 v[NE];
    #pragma unroll
    for (int e = 0; e < NE; e++) v[e] = *(const float4*)(ew + (size_t)e * (DI * (size_t)DM) + i);
    int idx = 0;
    #pragma unroll
    for (int lo = 0; lo < NE; lo++) {
      #pragma unroll
      for (int hi = lo + 1; hi < NE; hi++) {
        ushort4 pk;
        pk.x = f2b(0.5f * (v[lo].x + v[hi].x));
        pk.y = f2b(0.5f * (v[lo].y + v[hi].y));
        pk.z = f2b(0.5f * (v[lo].z + v[hi].z));
        pk.w = f2b(0.5f * (v[lo].w + v[hi].w));
        *(ushort4*)(wp + (size_t)idx * (DI * (size_t)DM) + i) = pk;
        idx++;
      }
    }
  }
}

// ---------------- grouped GEMM (pair path) + inline tile scheduler + fused k_var tail.
// y < 192: GEMM tile (wave-0 prefix scan over cnt reproduces the old k_sched table in LDS).
// y == 192 && x < 8: per-expert variance of softmax scores (runs in the gemm tail's idle CUs).
// R1-proven GEMM core: BK=64, 2-barrier K-loop, global_load_lds, XOR swizzle (chunk ^= row&7
// at the GLOBAL source), wave-uniform tail-skip. No min-occupancy bound (R3 spill lesson).
__global__ __launch_bounds__(256) void k_gemm_pair(
    const unsigned short* __restrict__ x16, const unsigned short* __restrict__ wp,
    const float* __restrict__ eb, const int* __restrict__ cnt,
    const int* __restrict__ ptok, const float* __restrict__ scores,
    float* __restrict__ out, float* __restrict__ vout)
{
  __shared__ __attribute__((aligned(16))) unsigned short As[128 * 64];
  __shared__ unsigned short Bs[128 * 64];
  __shared__ int s_tiles[2 * TILEY];
  __shared__ int s_nt;

  int tid  = threadIdx.x;

  if (blockIdx.y == TILEY) {
    // ---- fused k_var ----
    if (blockIdx.x >= 8) return;
    int e = blockIdx.x;
    double s = 0.0, s2 = 0.0;
    for (int t = tid; t < T_TOKENS; t += 256) {
      double v = (double)scores[(size_t)t * NE + e];
      s += v; s2 += v * v;
    }
    double* ls  = (double*)As;          // alias: 16KB >= 2*256*8B
    double* ls2 = ls + 256;
    ls[tid] = s; ls2[tid] = s2; __syncthreads();
    for (int st = 128; st > 0; st >>= 1) {
      if (tid < st) { ls[tid] += ls[tid + st]; ls2[tid] += ls2[tid + st]; }
      __syncthreads();
    }
    if (tid == 0) {
      double mean = ls[0] / (double)T_TOKENS;
      vout[e] = (float)((ls2[0] - ls[0] * mean) / (double)(T_TOKENS - 1));
    }
    return;
  }

  // ---- inline scheduler: wave 0 rebuilds the tile table (deterministic, identical per block)
  if (tid < 64) {
    int c  = cnt[tid];
    int nt = (c + 127) >> 7;
    int inc = nt;
    #pragma unroll
    for (int s = 1; s < 64; s <<= 1) {
      int v = __shfl_up(inc, s, 64);
      if (tid >= s) inc += v;
    }
    int excl = inc - nt;
    for (int i = 0; i < nt; i++) { s_tiles[2 * (excl + i)] = tid; s_tiles[2 * (excl + i) + 1] = i * 128; }
    if (tid == 63) s_nt = inc;
  }
  __syncthreads();

  int tileIdx = blockIdx.y;
  if (tileIdx >= s_nt) return;
  int p    = s_tiles[2 * tileIdx];
  int row0 = s_tiles[2 * tileIdx + 1];
  int e1 = p >> 3, e2 = p & 7;
  int pidx = e1 * 7 - ((e1 * (e1 - 1)) >> 1) + (e2 - e1 - 1);   // compact pair index 0..27
  int c  = cnt[p];
  int nTile = blockIdx.x;           // 0..31 over d_inner
  int lane = tid & 63;
  int wid  = tid >> 6;
  int waveM = wid >> 1, waveN = wid & 1;

  int rlim = c - row0 - waveM * 64;     // fragment mi live iff mi*16 < rlim

  int tok[4];
  #pragma unroll
  for (int i = 0; i < 4; i++) {
    int rg = row0 + (tid >> 3) + i * 32;
    if (rg > c - 1) rg = c - 1;
    tok[i] = ptok[p * CAP + rg];
  }

  f32x4 acc[4][4];
  #pragma unroll
  for (int i = 0; i < 4; i++)
    #pragma unroll
    for (int j = 0; j < 4; j++) acc[i][j] = {0.f, 0.f, 0.f, 0.f};

  const unsigned short* bb = wp + ((size_t)pidx * DI + (size_t)nTile * 128) * DM;

  for (int k0 = 0; k0 < DM; k0 += 64) {
    #pragma unroll
    for (int i = 0; i < 4; i++) {
      int r  = (tid >> 3) + i * 32;
      int cS = tid & 7;
      int kg = ((cS ^ (r & 7)) * 8);
      __builtin_amdgcn_global_load_lds(
          (const __attribute__((address_space(1))) void*)(x16 + (size_t)tok[i] * DM + k0 + kg),
          (__attribute__((address_space(3))) void*)(&As[r * 64 + cS * 8]), 16, 0, 0);
      __builtin_amdgcn_global_load_lds(
          (const __attribute__((address_space(1))) void*)(bb + (size_t)r * DM + k0 + kg),
          (__attribute__((address_space(3))) void*)(&Bs[r * 64 + cS * 8]), 16, 0, 0);
    }
    __syncthreads();
    #pragma unroll
    for (int kk = 0; kk < 2; kk++) {
      int q  = lane >> 4;
      int m  = lane & 15;
      int jg = kk * 4 + q;
      bf16x8 af[4], bf[4];
      #pragma unroll
      for (int mi = 0; mi < 4; mi++) {
        if (mi * 16 < rlim) {
          int R = waveM * 64 + mi * 16 + m;
          af[mi] = *(const bf16x8*)&As[R * 64 + ((jg ^ (R & 7)) * 8)];
        }
      }
      #pragma unroll
      for (int ni = 0; ni < 4; ni++) {
        int R = waveN * 64 + ni * 16 + m;
        bf[ni] = *(const bf16x8*)&Bs[R * 64 + ((jg ^ (R & 7)) * 8)];
      }
      #pragma unroll
      for (int mi = 0; mi < 4; mi++) {
        if (mi * 16 < rlim) {
          #pragma unroll
          for (int ni = 0; ni < 4; ni++)
            acc[mi][ni] = __builtin_amdgcn_mfma_f32_16x16x32_bf16(af[mi], bf[ni], acc[mi][ni], 0, 0, 0);
        }
      }
    }
    __syncthreads();
  }

  // epilogue: W_pair already carries the 0.5; biases still need it.
  int colbase = nTile * 128 + waveN * 64;
  float bsum[4];
  #pragma unroll
  for (int ni = 0; ni < 4; ni++) {
    int col = colbase + ni * 16 + (lane & 15);
    bsum[ni] = 0.5f * (eb[e1 * DI + col] + eb[e2 * DI + col]);
  }
  #pragma unroll
  for (int mi = 0; mi < 4; mi++) {
    #pragma unroll
    for (int r2 = 0; r2 < 4; r2++) {
      int row = waveM * 64 + mi * 16 + (lane >> 4) * 4 + r2;
      int rg = row0 + row;
      if (rg < c) {
        int t = ptok[p * CAP + rg];
        float* orow = out + (size_t)t * DI + colbase;
        #pragma unroll
        for (int ni = 0; ni < 4; ni++)
          orow[ni * 16 + (lane & 15)] = acc[mi][ni][r2] + bsum[ni];
      }
    }
  }
}

// ================= fallback path (R1-verified), used when workspace is too small =================

__global__ __launch_bounds__(256) void k_gating(
    const float* __restrict__ x, const float* __restrict__ gw, const float* __restrict__ gb,
    unsigned short* __restrict__ x16, float* __restrict__ scores,
    int* __restrict__ cnt, int* __restrict__ ptok)
{
  int wid  = (blockIdx.x * 256 + threadIdx.x) >> 6;
  int lane = threadIdx.x & 63;
  if (wid >= T_TOKENS) return;
  const float* xr = x + (size_t)wid * DM;
  double acc[NE];
  #pragma unroll
  for (int e = 0; e < NE; e++) acc[e] = 0.0;
  #pragma unroll
  for (int u = 0; u < 4; u++) {
    int off = u * 256 + lane * 4;
    float4 xv = *(const float4*)(xr + off);
    ushort4 pk; pk.x = f2b(xv.x); pk.y = f2b(xv.y); pk.z = f2b(xv.z); pk.w = f2b(xv.w);
    *(ushort4*)(x16 + (size_t)wid * DM + off) = pk;
    #pragma unroll
    for (int e = 0; e < NE; e++) {
      float4 wv = *(const float4*)(gw + e * DM + off);
      acc[e] += (double)xv.x * wv.x + (double)xv.y * wv.y
              + (double)xv.z * wv.z + (double)xv.w * wv.w;
    }
  }
  #pragma unroll
  for (int e = 0; e < NE; e++) {
    double v = acc[e];
    #pragma unroll
    for (int s = 32; s > 0; s >>= 1) v += __shfl_xor(v, s, 64);
    acc[e] = v + (double)gb[e];
  }
  if (lane == 0) {
    double m = acc[0];
    for (int e = 1; e < NE; e++) if (acc[e] > m) m = acc[e];
    double ex[NE], sum = 0.0;
    for (int e = 0; e < NE; e++) { ex[e] = exp(acc[e] - m); sum += ex[e]; }
    double inv = 1.0 / sum;
    for (int e = 0; e < NE; e++) scores[(size_t)wid * NE + e] = (float)(ex[e] * inv);
    int e1 = 0; double b1 = acc[0];
    for (int e = 1; e < NE; e++) if (acc[e] > b1) { b1 = acc[e]; e1 = e; }
    int e2 = -1; double b2 = -1e300;
    for (int e = 0; e < NE; e++) if (e != e1 && acc[e] > b2) { b2 = acc[e]; e2 = e; }
    int lo = e1 < e2 ? e1 : e2, hi = e1 < e2 ? e2 : e1;
    int p = lo * 8 + hi;
    int pos = atomicAdd(&cnt[p], 1);
    ptok[p * CAP + pos] = wid;
  }
}

__global__ __launch_bounds__(256) void k_wconv(const float* __restrict__ w, unsigned short* __restrict__ w16) {
  size_t i = ((size_t)blockIdx.x * 256 + threadIdx.x) * 8;
  float4 a = *(const float4*)(w + i);
  float4 b = *(const float4*)(w + i + 4);
  ushort4 pa, pb;
  pa.x = f2b(a.x); pa.y = f2b(a.y); pa.z = f2b(a.z); pa.w = f2b(a.w);
  pb.x = f2b(b.x); pb.y = f2b(b.y); pb.z = f2b(b.z); pb.w = f2b(b.w);
  *(ushort4*)(w16 + i) = pa;
  *(ushort4*)(w16 + i + 4) = pb;
}

__global__ void k_sched(const int* __restrict__ cnt, int* __restrict__ tiles, int* __restrict__ ntiles) {
  int p = threadIdx.x;
  int c = cnt[p];
  int nt = (c + 127) >> 7;
  int inc = nt;
  #pragma unroll
  for (int s = 1; s < 64; s <<= 1) {
    int v = __shfl_up(inc, s, 64);
    if (p >= s) inc += v;
  }
  int excl = inc - nt;
  for (int i = 0; i < nt; i++) { tiles[2 * (excl + i)] = p; tiles[2 * (excl + i) + 1] = i * 128; }
  if (p == 63) *ntiles = inc;
}

__global__ __launch_bounds__(256) void k_gemm_dual(
    const unsigned short* __restrict__ x16, const unsigned short* __restrict__ w16,
    const float* __restrict__ eb, const int* __restrict__ cnt,
    const int* __restrict__ ptok, const int* __restrict__ tiles, const int* __restrict__ ntiles,
    float* __restrict__ out)
{
  __shared__ unsigned short As[128 * 64];
  __shared__ unsigned short Bs[2][128 * 64];

  int tileIdx = blockIdx.y;
  if (tileIdx >= *ntiles) return;
  int p    = tiles[2 * tileIdx];
  int row0 = tiles[2 * tileIdx + 1];
  int e1 = p >> 3, e2 = p & 7;
  int c  = cnt[p];
  int nTile = blockIdx.x;
  int tid  = threadIdx.x;
  int lane = tid & 63;
  int wid  = tid >> 6;
  int waveM = wid >> 1, waveN = wid & 1;
  int rlim = c - row0 - waveM * 64;

  int tok[4];
  #pragma unroll
  for (int i = 0; i < 4; i++) {
    int rg = row0 + (tid >> 3) + i * 32;
    if (rg > c - 1) rg = c - 1;
    tok[i] = ptok[p * CAP + rg];
  }

  f32x4 acc[4][4];
  #pragma unroll
  for (int i = 0; i < 4; i++)
    #pragma unroll
    for (int j = 0; j < 4; j++) acc[i][j] = {0.f, 0.f, 0.f, 0.f};

  const unsigned short* bb1 = w16 + ((size_t)e1 * DI + (size_t)nTile * 128) * DM;
  const unsigned short* bb2 = w16 + ((size_t)e2 * DI + (size_t)nTile * 128) * DM;

  for (int k0 = 0; k0 < DM; k0 += 64) {
    #pragma unroll
    for (int i = 0; i < 4; i++) {
      int r  = (tid >> 3) + i * 32;
      int cS = tid & 7;
      int kg = ((cS ^ (r & 7)) * 8);
      __builtin_amdgcn_global_load_lds(
          (const __attribute__((address_space(1))) void*)(x16 + (size_t)tok[i] * DM + k0 + kg),
          (__attribute__((address_space(3))) void*)(&As[r * 64 + cS * 8]), 16, 0, 0);
      __builtin_amdgcn_global_load_lds(
          (const __attribute__((address_space(1))) void*)(bb1 + (size_t)r * DM + k0 + kg),
          (__attribute__((address_space(3))) void*)(&Bs[0][r * 64 + cS * 8]), 16, 0, 0);
      __builtin_amdgcn_global_load_lds(
          (const __attribute__((address_space(1))) void*)(bb2 + (size_t)r * DM + k0 + kg),
          (__attribute__((address_space(3))) void*)(&Bs[1][r * 64 + cS * 8]), 16, 0, 0);
    }
    __syncthreads();
    #pragma unroll
    for (int kk = 0; kk < 2; kk++) {
      int q  = lane >> 4;
      int m  = lane & 15;
      int jg = kk * 4 + q;
      bf16x8 af[4], bf0[4], bf1[4];
      #pragma unroll
      for (int mi = 0; mi < 4; mi++) {
        if (mi * 16 < rlim) {
          int R = waveM * 64 + mi * 16 + m;
          af[mi] = *(const bf16x8*)&As[R * 64 + ((jg ^ (R & 7)) * 8)];
        }
      }
      #pragma unroll
      for (int ni = 0; ni < 4; ni++) {
        int R = waveN * 64 + ni * 16 + m;
        int o = R * 64 + ((jg ^ (R & 7)) * 8);
        bf0[ni] = *(const bf16x8*)&Bs[0][o];
        bf1[ni] = *(const bf16x8*)&Bs[1][o];
      }
      #pragma unroll
      for (int mi = 0; mi < 4; mi++) {
        if (mi * 16 < rlim) {
          #pragma unroll
          for (int ni = 0; ni < 4; ni++) {
            acc[mi][ni] = __builtin_amdgcn_mfma_f32_16x16x32_bf16(af[mi], bf0[ni], acc[mi][ni], 0, 0, 0);
            acc[mi][ni] = __builtin_amdgcn_mfma_f32_16x16x32_bf16(af[mi], bf1[ni], acc[mi][ni], 0, 0, 0);
          }
        }
      }
    }
    __syncthreads();
  }

  int colbase = nTile * 128 + waveN * 64;
  float bsum[4];
  #pragma unroll
  for (int ni = 0; ni < 4; ni++) {
    int col = colbase + ni * 16 + (lane & 15);
    bsum[ni] = 0.5f * (eb[e1 * DI + col] + eb[e2 * DI + col]);
  }
  #pragma unroll
  for (int mi = 0; mi < 4; mi++) {
    #pragma unroll
    for (int r2 = 0; r2 < 4; r2++) {
      int row = waveM * 64 + mi * 16 + (lane >> 4) * 4 + r2;
      int rg = row0 + row;
      if (rg < c) {
        int t = ptok[p * CAP + rg];
        float* orow = out + (size_t)t * DI + colbase;
        #pragma unroll
        for (int ni = 0; ni < 4; ni++)
          orow[ni * 16 + (lane & 15)] = 0.5f * acc[mi][ni][r2] + bsum[ni];
      }
    }
  }
}

__global__ __launch_bounds__(256) void k_var(const float* __restrict__ scores, float* __restrict__ vout) {
  int e = blockIdx.x, tid = threadIdx.x;
  double s = 0.0, s2 = 0.0;
  for (int t = tid; t < T_TOKENS; t += 256) {
    double v = (double)scores[(size_t)t * NE + e];
    s += v; s2 += v * v;
  }
  __shared__ double ls[256], ls2[256];
  ls[tid] = s; ls2[tid] = s2; __syncthreads();
  for (int st = 128; st > 0; st >>= 1) {
    if (tid < st) { ls[tid] += ls[tid + st]; ls2[tid] += ls2[tid + st]; }
    __syncthreads();
  }
  if (tid == 0) {
    double mean = ls[0] / (double)T_TOKENS;
    vout[e] = (float)((ls2[0] - ls[0] * mean) / (double)(T_TOKENS - 1));
  }
}

extern "C" void kernel_launch(void* const* d_in, const int* in_sizes, int n_in,
                              void* d_out, int out_size, void* d_ws, size_t ws_size,
                              hipStream_t stream)
{
  const float* x  = (const float*)d_in[0];
  const float* gw = (const float*)d_in[1];
  const float* gb = (const float*)d_in[2];
  const float* ew = (const float*)d_in[3];
  const float* eb = (const float*)d_in[4];
  float* out = (float*)d_out;
  char* ws = (char*)d_ws;

  // ---- pair path workspace (273.2 MB) ----
  const size_t OFF_WPAIR  = 33554432ull;                              // after x16 (33.5 MB)
  const size_t OFF_SCORES = OFF_WPAIR + (size_t)NPAIRC * DI * DM * 2; // +234,881,024
  const size_t OFF_PTOK   = OFF_SCORES + 524288ull;
  const size_t OFF_CNT    = OFF_PTOK + 4194304ull;
  const size_t OFF_NT     = OFF_CNT + 256ull;
  const size_t OFF_TILES  = OFF_NT + 16ull;
  const size_t NEED_PAIR  = OFF_TILES + 1536ull;

  if (ws_size >= NEED_PAIR) {
    unsigned short* x16 = (unsigned short*)ws;
    unsigned short* wp  = (unsigned short*)(ws + OFF_WPAIR);
    float* scores       = (float*)(ws + OFF_SCORES);
    int*   ptok         = (int*)(ws + OFF_PTOK);
    int*   cnt          = (int*)(ws + OFF_CNT);

    hipMemsetAsync(cnt, 0, PAIRS * sizeof(int), stream);
    k_prep<<<dim3(8192), dim3(256), 0, stream>>>(x, gw, gb, ew, x16, wp, scores, cnt, ptok);
    k_gemm_pair<<<dim3(32, TILEY + 1), dim3(256), 0, stream>>>(
        x16, wp, eb, cnt, ptok, scores, out, out + 67108864);
  } else {
    // ---- fallback: R1-verified layout (~105.4 MB) ----
    unsigned short* x16 = (unsigned short*)ws;
    unsigned short* w16 = (unsigned short*)(ws + 33554432);
    float* scores       = (float*)(ws + 100663296);
    int*   ptok         = (int*)(ws + 101187584);
    int*   cnt          = (int*)(ws + 105381888);
    int*   ntiles       = (int*)(ws + 105382144);
    int*   tiles        = (int*)(ws + 105382160);

    hipMemsetAsync(cnt, 0, PAIRS * sizeof(int), stream);
    k_gating<<<dim3(4096), dim3(256), 0, stream>>>(x, gw, gb, x16, scores, cnt, ptok);
    k_wconv <<<dim3(16384), dim3(256), 0, stream>>>(ew, w16);
    k_sched <<<dim3(1), dim3(64), 0, stream>>>(cnt, tiles, ntiles);
    k_gemm_dual<<<dim3(32, 192), dim3(256), 0, stream>>>(x16, w16, eb, cnt, ptok, tiles, ntiles, out);
    k_var   <<<dim3(8), dim3(256), 0, stream>>>(scores, out + 67108864);
  }
}

// Round 8
// 741.879 us; speedup vs baseline: 2.0079x; 1.0019x over previous
//
#include <hip/hip_runtime.h>

#define T_TOKENS 16384
#define DM 1024      // d_model
#define DI 4096      // d_inner
#define NE 8
#define PAIRS 64     // sparse pair slots: p = lo*8+hi, lo<hi
#define NPAIRC 28    // compact active pairs (lo<hi)
#define CAP 16384    // max tokens per pair
#define TILEY 192    // max tiles: sum ceil(c_p/128) <= 128+64 = 192

typedef float f32x4 __attribute__((ext_vector_type(4)));
typedef __bf16 bf16x8 __attribute__((ext_vector_type(8)));

__device__ inline unsigned short f2b(float f) {
  union { float f; unsigned u; } v; v.f = f;
  unsigned r = v.u + 0x7FFFu + ((v.u >> 16) & 1u);   // round-to-nearest-even bf16
  return (unsigned short)(r >> 16);
}

// ---------------- fused prep: blocks 0..4095 = gating (fp64 logits -> softmax, top-2 -> pair
// lists, emit bf16 X); blocks 4096..8191 = pair-averaged weights wp = bf16(0.5*(W_lo+W_hi)).
__global__ __launch_bounds__(256) void k_prep(
    const float* __restrict__ x, const float* __restrict__ gw, const float* __restrict__ gb,
    const float* __restrict__ ew,
    unsigned short* __restrict__ x16, unsigned short* __restrict__ wp,
    float* __restrict__ scores, int* __restrict__ cnt, int* __restrict__ ptok)
{
  if (blockIdx.x < 4096) {
    // ---- gating ----
    int wid  = (blockIdx.x * 256 + threadIdx.x) >> 6;   // one wave per token
    int lane = threadIdx.x & 63;
    if (wid >= T_TOKENS) return;
    const float* xr = x + (size_t)wid * DM;

    double acc[NE];
    #pragma unroll
    for (int e = 0; e < NE; e++) acc[e] = 0.0;

    #pragma unroll
    for (int u = 0; u < 4; u++) {
      int off = u * 256 + lane * 4;
      float4 xv = *(const float4*)(xr + off);
      ushort4 pk; pk.x = f2b(xv.x); pk.y = f2b(xv.y); pk.z = f2b(xv.z); pk.w = f2b(xv.w);
      *(ushort4*)(x16 + (size_t)wid * DM + off) = pk;
      #pragma unroll
      for (int e = 0; e < NE; e++) {
        float4 wv = *(const float4*)(gw + e * DM + off);
        acc[e] += (double)xv.x * wv.x + (double)xv.y * wv.y
                + (double)xv.z * wv.z + (double)xv.w * wv.w;
      }
    }
    #pragma unroll
    for (int e = 0; e < NE; e++) {
      double v = acc[e];
      #pragma unroll
      for (int s = 32; s > 0; s >>= 1) v += __shfl_xor(v, s, 64);
      acc[e] = v + (double)gb[e];
    }
    if (lane == 0) {
      double m = acc[0];
      for (int e = 1; e < NE; e++) if (acc[e] > m) m = acc[e];
      double ex[NE], sum = 0.0;
      for (int e = 0; e < NE; e++) { ex[e] = exp(acc[e] - m); sum += ex[e]; }
      double inv = 1.0 / sum;
      for (int e = 0; e < NE; e++) scores[(size_t)wid * NE + e] = (float)(ex[e] * inv);
      int e1 = 0; double b1 = acc[0];
      for (int e = 1; e < NE; e++) if (acc[e] > b1) { b1 = acc[e]; e1 = e; }
      int e2 = -1; double b2 = -1e300;
      for (int e = 0; e < NE; e++) if (e != e1 && acc[e] > b2) { b2 = acc[e]; e2 = e; }
      int lo = e1 < e2 ? e1 : e2, hi = e1 < e2 ? e2 : e1;
      int p = lo * 8 + hi;
      int pos = atomicAdd(&cnt[p], 1);
      ptok[p * CAP + pos] = wid;
    }
  } else {
    // ---- wpair ----
    size_t i = (((size_t)blockIdx.x - 4096) * 256 + threadIdx.x) * 4;  // float4 index in one DI*DM matrix
    float4 v[NE];
    #pragma unroll
    for (int e = 0; e < NE; e++) v[e] = *(const float4*)(ew + (size_t)e * (DI * (size_t)DM) + i);
    int idx = 0;
    #pragma unroll
    for (int lo = 0; lo < NE; lo++) {
      #pragma unroll
      for (int hi = lo + 1; hi < NE; hi++) {
        ushort4 pk;
        pk.x = f2b(0.5f * (v[lo].x + v[hi].x));
        pk.y = f2b(0.5f * (v[lo].y + v[hi].y));
        pk.z = f2b(0.5f * (v[lo].z + v[hi].z));
        pk.w = f2b(0.5f * (v[lo].w + v[hi].w));
        *(ushort4*)(wp + (size_t)idx * (DI * (size_t)DM) + i) = pk;
        idx++;
      }
    }
  }
}

// ---------------- grouped GEMM (pair path) + per-wave ballot scheduler + fused k_var tail.
// y < TILEY: GEMM tile. Each WAVE independently rebuilds the tile mapping from cnt[] with a
// register prefix-scan + ballot (no LDS table, no extra barrier — R5's LDS table pushed the
// block past the 32KB/5-block boundary and serialized startup; this is ~80 cycles in regs).
// y == TILEY && x < 8: per-expert variance of softmax scores (runs in the gemm tail).
// R1-proven GEMM core: BK=64, 2-barrier K-loop, global_load_lds, XOR swizzle (chunk ^= row&7
// at the GLOBAL source), wave-uniform tail-skip. No min-occupancy bound (R3 spill lesson).
__global__ __launch_bounds__(256) void k_gemm_pair(
    const unsigned short* __restrict__ x16, const unsigned short* __restrict__ wp,
    const float* __restrict__ eb, const int* __restrict__ cnt,
    const int* __restrict__ ptok, const float* __restrict__ scores,
    float* __restrict__ out, float* __restrict__ vout)
{
  __shared__ __attribute__((aligned(16))) unsigned short As[128 * 64];
  __shared__ unsigned short Bs[128 * 64];

  int tid  = threadIdx.x;

  if (blockIdx.y == TILEY) {
    // ---- fused k_var ----
    if (blockIdx.x >= 8) return;
    int e = blockIdx.x;
    double s = 0.0, s2 = 0.0;
    for (int t = tid; t < T_TOKENS; t += 256) {
      double v = (double)scores[(size_t)t * NE + e];
      s += v; s2 += v * v;
    }
    double* ls  = (double*)As;          // alias: 16KB >= 2*256*8B
    double* ls2 = ls + 256;
    ls[tid] = s; ls2[tid] = s2; __syncthreads();
    for (int st = 128; st > 0; st >>= 1) {
      if (tid < st) { ls[tid] += ls[tid + st]; ls2[tid] += ls2[tid + st]; }
      __syncthreads();
    }
    if (tid == 0) {
      double mean = ls[0] / (double)T_TOKENS;
      vout[e] = (float)((ls2[0] - ls[0] * mean) / (double)(T_TOKENS - 1));
    }
    return;
  }

  // ---- per-wave ballot scheduler: lane p holds cnt[p]; prefix-scan tile counts; the lane
  // whose [excl,inc) span contains tileIdx is this block's pair. All waves compute identically.
  int lane = tid & 63;
  int cw  = cnt[lane];
  int nt  = (cw + 127) >> 7;
  int inc = nt;
  #pragma unroll
  for (int s = 1; s < 64; s <<= 1) {
    int v = __shfl_up(inc, s, 64);
    if (lane >= s) inc += v;
  }
  int total = __shfl(inc, 63, 64);
  int tileIdx = blockIdx.y;
  if (tileIdx >= total) return;
  int excl = inc - nt;
  unsigned long long bm = __ballot(tileIdx >= excl && tileIdx < inc);
  int p = (int)__builtin_ctzll(bm);
  int row0 = (tileIdx - __shfl(excl, p, 64)) * 128;
  int c    = __shfl(cw, p, 64);

  int e1 = p >> 3, e2 = p & 7;
  int pidx = e1 * 7 - ((e1 * (e1 - 1)) >> 1) + (e2 - e1 - 1);   // compact pair index 0..27
  int nTile = blockIdx.x;           // 0..31 over d_inner
  int wid  = tid >> 6;
  int waveM = wid >> 1, waveN = wid & 1;

  int rlim = c - row0 - waveM * 64;     // fragment mi live iff mi*16 < rlim

  int tok[4];
  #pragma unroll
  for (int i = 0; i < 4; i++) {
    int rg = row0 + (tid >> 3) + i * 32;
    if (rg > c - 1) rg = c - 1;
    tok[i] = ptok[p * CAP + rg];
  }

  f32x4 acc[4][4];
  #pragma unroll
  for (int i = 0; i < 4; i++)
    #pragma unroll
    for (int j = 0; j < 4; j++) acc[i][j] = {0.f, 0.f, 0.f, 0.f};

  const unsigned short* bb = wp + ((size_t)pidx * DI + (size_t)nTile * 128) * DM;

  for (int k0 = 0; k0 < DM; k0 += 64) {
    #pragma unroll
    for (int i = 0; i < 4; i++) {
      int r  = (tid >> 3) + i * 32;
      int cS = tid & 7;
      int kg = ((cS ^ (r & 7)) * 8);
      __builtin_amdgcn_global_load_lds(
          (const __attribute__((address_space(1))) void*)(x16 + (size_t)tok[i] * DM + k0 + kg),
          (__attribute__((address_space(3))) void*)(&As[r * 64 + cS * 8]), 16, 0, 0);
      __builtin_amdgcn_global_load_lds(
          (const __attribute__((address_space(1))) void*)(bb + (size_t)r * DM + k0 + kg),
          (__attribute__((address_space(3))) void*)(&Bs[r * 64 + cS * 8]), 16, 0, 0);
    }
    __syncthreads();
    #pragma unroll
    for (int kk = 0; kk < 2; kk++) {
      int q  = lane >> 4;
      int m  = lane & 15;
      int jg = kk * 4 + q;
      bf16x8 af[4], bf[4];
      #pragma unroll
      for (int mi = 0; mi < 4; mi++) {
        if (mi * 16 < rlim) {
          int R = waveM * 64 + mi * 16 + m;
          af[mi] = *(const bf16x8*)&As[R * 64 + ((jg ^ (R & 7)) * 8)];
        }
      }
      #pragma unroll
      for (int ni = 0; ni < 4; ni++) {
        int R = waveN * 64 + ni * 16 + m;
        bf[ni] = *(const bf16x8*)&Bs[R * 64 + ((jg ^ (R & 7)) * 8)];
      }
      #pragma unroll
      for (int mi = 0; mi < 4; mi++) {
        if (mi * 16 < rlim) {
          #pragma unroll
          for (int ni = 0; ni < 4; ni++)
            acc[mi][ni] = __builtin_amdgcn_mfma_f32_16x16x32_bf16(af[mi], bf[ni], acc[mi][ni], 0, 0, 0);
        }
      }
    }
    __syncthreads();
  }

  // epilogue: W_pair already carries the 0.5; biases still need it.
  int colbase = nTile * 128 + waveN * 64;
  float bsum[4];
  #pragma unroll
  for (int ni = 0; ni < 4; ni++) {
    int col = colbase + ni * 16 + (lane & 15);
    bsum[ni] = 0.5f * (eb[e1 * DI + col] + eb[e2 * DI + col]);
  }
  #pragma unroll
  for (int mi = 0; mi < 4; mi++) {
    #pragma unroll
    for (int r2 = 0; r2 < 4; r2++) {
      int row = waveM * 64 + mi * 16 + (lane >> 4) * 4 + r2;
      int rg = row0 + row;
      if (rg < c) {
        int t = ptok[p * CAP + rg];
        float* orow = out + (size_t)t * DI + colbase;
        #pragma unroll
        for (int ni = 0; ni < 4; ni++)
          orow[ni * 16 + (lane & 15)] = acc[mi][ni][r2] + bsum[ni];
      }
    }
  }
}

// ================= fallback path (R1-verified), used when workspace is too small =================

__global__ __launch_bounds__(256) void k_gating(
    const float* __restrict__ x, const float* __restrict__ gw, const float* __restrict__ gb,
    unsigned short* __restrict__ x16, float* __restrict__ scores,
    int* __restrict__ cnt, int* __restrict__ ptok)
{
  int wid  = (blockIdx.x * 256 + threadIdx.x) >> 6;
  int lane = threadIdx.x & 63;
  if (wid >= T_TOKENS) return;
  const float* xr = x + (size_t)wid * DM;
  double acc[NE];
  #pragma unroll
  for (int e = 0; e < NE; e++) acc[e] = 0.0;
  #pragma unroll
  for (int u = 0; u < 4; u++) {
    int off = u * 256 + lane * 4;
    float4 xv = *(const float4*)(xr + off);
    ushort4 pk; pk.x = f2b(xv.x); pk.y = f2b(xv.y); pk.z = f2b(xv.z); pk.w = f2b(xv.w);
    *(ushort4*)(x16 + (size_t)wid * DM + off) = pk;
    #pragma unroll
    for (int e = 0; e < NE; e++) {
      float4 wv = *(const float4*)(gw + e * DM + off);
      acc[e] += (double)xv.x * wv.x + (double)xv.y * wv.y
              + (double)xv.z * wv.z + (double)xv.w * wv.w;
    }
  }
  #pragma unroll
  for (int e = 0; e < NE; e++) {
    double v = acc[e];
    #pragma unroll
    for (int s = 32; s > 0; s >>= 1) v += __shfl_xor(v, s, 64);
    acc[e] = v + (double)gb[e];
  }
  if (lane == 0) {
    double m = acc[0];
    for (int e = 1; e < NE; e++) if (acc[e] > m) m = acc[e];
    double ex[NE], sum = 0.0;
    for (int e = 0; e < NE; e++) { ex[e] = exp(acc[e] - m); sum += ex[e]; }
    double inv = 1.0 / sum;
    for (int e = 0; e < NE; e++) scores[(size_t)wid * NE + e] = (float)(ex[e] * inv);
    int e1 = 0; double b1 = acc[0];
    for (int e = 1; e < NE; e++) if (acc[e] > b1) { b1 = acc[e]; e1 = e; }
    int e2 = -1; double b2 = -1e300;
    for (int e = 0; e < NE; e++) if (e != e1 && acc[e] > b2) { b2 = acc[e]; e2 = e; }
    int lo = e1 < e2 ? e1 : e2, hi = e1 < e2 ? e2 : e1;
    int p = lo * 8 + hi;
    int pos = atomicAdd(&cnt[p], 1);
    ptok[p * CAP + pos] = wid;
  }
}

__global__ __launch_bounds__(256) void k_wconv(const float* __restrict__ w, unsigned short* __restrict__ w16) {
  size_t i = ((size_t)blockIdx.x * 256 + threadIdx.x) * 8;
  float4 a = *(const float4*)(w + i);
  float4 b = *(const float4*)(w + i + 4);
  ushort4 pa, pb;
  pa.x = f2b(a.x); pa.y = f2b(a.y); pa.z = f2b(a.z); pa.w = f2b(a.w);
  pb.x = f2b(b.x); pb.y = f2b(b.y); pb.z = f2b(b.z); pb.w = f2b(b.w);
  *(ushort4*)(w16 + i) = pa;
  *(ushort4*)(w16 + i + 4) = pb;
}

__global__ void k_sched(const int* __restrict__ cnt, int* __restrict__ tiles, int* __restrict__ ntiles) {
  int p = threadIdx.x;
  int c = cnt[p];
  int nt = (c + 127) >> 7;
  int inc = nt;
  #pragma unroll
  for (int s = 1; s < 64; s <<= 1) {
    int v = __shfl_up(inc, s, 64);
    if (p >= s) inc += v;
  }
  int excl = inc - nt;
  for (int i = 0; i < nt; i++) { tiles[2 * (excl + i)] = p; tiles[2 * (excl + i) + 1] = i * 128; }
  if (p == 63) *ntiles = inc;
}

__global__ __launch_bounds__(256) void k_gemm_dual(
    const unsigned short* __restrict__ x16, const unsigned short* __restrict__ w16,
    const float* __restrict__ eb, const int* __restrict__ cnt,
    const int* __restrict__ ptok, const int* __restrict__ tiles, const int* __restrict__ ntiles,
    float* __restrict__ out)
{
  __shared__ unsigned short As[128 * 64];
  __shared__ unsigned short Bs[2][128 * 64];

  int tileIdx = blockIdx.y;
  if (tileIdx >= *ntiles) return;
  int p    = tiles[2 * tileIdx];
  int row0 = tiles[2 * tileIdx + 1];
  int e1 = p >> 3, e2 = p & 7;
  int c  = cnt[p];
  int nTile = blockIdx.x;
  int tid  = threadIdx.x;
  int lane = tid & 63;
  int wid  = tid >> 6;
  int waveM = wid >> 1, waveN = wid & 1;
  int rlim = c - row0 - waveM * 64;

  int tok[4];
  #pragma unroll
  for (int i = 0; i < 4; i++) {
    int rg = row0 + (tid >> 3) + i * 32;
    if (rg > c - 1) rg = c - 1;
    tok[i] = ptok[p * CAP + rg];
  }

  f32x4 acc[4][4];
  #pragma unroll
  for (int i = 0; i < 4; i++)
    #pragma unroll
    for (int j = 0; j < 4; j++) acc[i][j] = {0.f, 0.f, 0.f, 0.f};

  const unsigned short* bb1 = w16 + ((size_t)e1 * DI + (size_t)nTile * 128) * DM;
  const unsigned short* bb2 = w16 + ((size_t)e2 * DI + (size_t)nTile * 128) * DM;

  for (int k0 = 0; k0 < DM; k0 += 64) {
    #pragma unroll
    for (int i = 0; i < 4; i++) {
      int r  = (tid >> 3) + i * 32;
      int cS = tid & 7;
      int kg = ((cS ^ (r & 7)) * 8);
      __builtin_amdgcn_global_load_lds(
          (const __attribute__((address_space(1))) void*)(x16 + (size_t)tok[i] * DM + k0 + kg),
          (__attribute__((address_space(3))) void*)(&As[r * 64 + cS * 8]), 16, 0, 0);
      __builtin_amdgcn_global_load_lds(
          (const __attribute__((address_space(1))) void*)(bb1 + (size_t)r * DM + k0 + kg),
          (__attribute__((address_space(3))) void*)(&Bs[0][r * 64 + cS * 8]), 16, 0, 0);
      __builtin_amdgcn_global_load_lds(
          (const __attribute__((address_space(1))) void*)(bb2 + (size_t)r * DM + k0 + kg),
          (__attribute__((address_space(3))) void*)(&Bs[1][r * 64 + cS * 8]), 16, 0, 0);
    }
    __syncthreads();
    #pragma unroll
    for (int kk = 0; kk < 2; kk++) {
      int q  = lane >> 4;
      int m  = lane & 15;
      int jg = kk * 4 + q;
      bf16x8 af[4], bf0[4], bf1[4];
      #pragma unroll
      for (int mi = 0; mi < 4; mi++) {
        if (mi * 16 < rlim) {
          int R = waveM * 64 + mi * 16 + m;
          af[mi] = *(const bf16x8*)&As[R * 64 + ((jg ^ (R & 7)) * 8)];
        }
      }
      #pragma unroll
      for (int ni = 0; ni < 4; ni++) {
        int R = waveN * 64 + ni * 16 + m;
        int o = R * 64 + ((jg ^ (R & 7)) * 8);
        bf0[ni] = *(const bf16x8*)&Bs[0][o];
        bf1[ni] = *(const bf16x8*)&Bs[1][o];
      }
      #pragma unroll
      for (int mi = 0; mi < 4; mi++) {
        if (mi * 16 < rlim) {
          #pragma unroll
          for (int ni = 0; ni < 4; ni++) {
            acc[mi][ni] = __builtin_amdgcn_mfma_f32_16x16x32_bf16(af[mi], bf0[ni], acc[mi][ni], 0, 0, 0);
            acc[mi][ni] = __builtin_amdgcn_mfma_f32_16x16x32_bf16(af[mi], bf1[ni], acc[mi][ni], 0, 0, 0);
          }
        }
      }
    }
    __syncthreads();
  }

  int colbase = nTile * 128 + waveN * 64;
  float bsum[4];
  #pragma unroll
  for (int ni = 0; ni < 4; ni++) {
    int col = colbase + ni * 16 + (lane & 15);
    bsum[ni] = 0.5f * (eb[e1 * DI + col] + eb[e2 * DI + col]);
  }
  #pragma unroll
  for (int mi = 0; mi < 4; mi++) {
    #pragma unroll
    for (int r2 = 0; r2 < 4; r2++) {
      int row = waveM * 64 + mi * 16 + (lane >> 4) * 4 + r2;
      int rg = row0 + row;
      if (rg < c) {
        int t = ptok[p * CAP + rg];
        float* orow = out + (size_t)t * DI + colbase;
        #pragma unroll
        for (int ni = 0; ni < 4; ni++)
          orow[ni * 16 + (lane & 15)] = 0.5f * acc[mi][ni][r2] + bsum[ni];
      }
    }
  }
}

__global__ __launch_bounds__(256) void k_var(const float* __restrict__ scores, float* __restrict__ vout) {
  int e = blockIdx.x, tid = threadIdx.x;
  double s = 0.0, s2 = 0.0;
  for (int t = tid; t < T_TOKENS; t += 256) {
    double v = (double)scores[(size_t)t * NE + e];
    s += v; s2 += v * v;
  }
  __shared__ double ls[256], ls2[256];
  ls[tid] = s; ls2[tid] = s2; __syncthreads();
  for (int st = 128; st > 0; st >>= 1) {
    if (tid < st) { ls[tid] += ls[tid + st]; ls2[tid] += ls2[tid + st]; }
    __syncthreads();
  }
  if (tid == 0) {
    double mean = ls[0] / (double)T_TOKENS;
    vout[e] = (float)((ls2[0] - ls[0] * mean) / (double)(T_TOKENS - 1));
  }
}

extern "C" void kernel_launch(void* const* d_in, const int* in_sizes, int n_in,
                              void* d_out, int out_size, void* d_ws, size_t ws_size,
                              hipStream_t stream)
{
  const float* x  = (const float*)d_in[0];
  const float* gw = (const float*)d_in[1];
  const float* gb = (const float*)d_in[2];
  const float* ew = (const float*)d_in[3];
  const float* eb = (const float*)d_in[4];
  float* out = (float*)d_out;
  char* ws = (char*)d_ws;

  // ---- pair path workspace (273.2 MB) ----
  const size_t OFF_WPAIR  = 33554432ull;                              // after x16 (33.5 MB)
  const size_t OFF_SCORES = OFF_WPAIR + (size_t)NPAIRC * DI * DM * 2; // +234,881,024
  const size_t OFF_PTOK   = OFF_SCORES + 524288ull;
  const size_t OFF_CNT    = OFF_PTOK + 4194304ull;
  const size_t OFF_NT     = OFF_CNT + 256ull;
  const size_t OFF_TILES  = OFF_NT + 16ull;
  const size_t NEED_PAIR  = OFF_TILES + 1536ull;

  if (ws_size >= NEED_PAIR) {
    unsigned short* x16 = (unsigned short*)ws;
    unsigned short* wp  = (unsigned short*)(ws + OFF_WPAIR);
    float* scores       = (float*)(ws + OFF_SCORES);
    int*   ptok         = (int*)(ws + OFF_PTOK);
    int*   cnt          = (int*)(ws + OFF_CNT);

    hipMemsetAsync(cnt, 0, PAIRS * sizeof(int), stream);
    k_prep<<<dim3(8192), dim3(256), 0, stream>>>(x, gw, gb, ew, x16, wp, scores, cnt, ptok);
    k_gemm_pair<<<dim3(32, TILEY + 1), dim3(256), 0, stream>>>(
        x16, wp, eb, cnt, ptok, scores, out, out + 67108864);
  } else {
    // ---- fallback: R1-verified layout (~105.4 MB) ----
    unsigned short* x16 = (unsigned short*)ws;
    unsigned short* w16 = (unsigned short*)(ws + 33554432);
    float* scores       = (float*)(ws + 100663296);
    int*   ptok         = (int*)(ws + 101187584);
    int*   cnt          = (int*)(ws + 105381888);
    int*   ntiles       = (int*)(ws + 105382144);
    int*   tiles        = (int*)(ws + 105382160);

    hipMemsetAsync(cnt, 0, PAIRS * sizeof(int), stream);
    k_gating<<<dim3(4096), dim3(256), 0, stream>>>(x, gw, gb, x16, scores, cnt, ptok);
    k_wconv <<<dim3(16384), dim3(256), 0, stream>>>(ew, w16);
    k_sched <<<dim3(1), dim3(64), 0, stream>>>(cnt, tiles, ntiles);
    k_gemm_dual<<<dim3(32, 192), dim3(256), 0, stream>>>(x16, w16, eb, cnt, ptok, tiles, ntiles, out);
    k_var   <<<dim3(8), dim3(256), 0, stream>>>(scores, out + 67108864);
  }
}